// Round 8
// baseline (22425.157 us; speedup 1.0000x reference)
//
#include <hip/hip_runtime.h>
#include <stdint.h>

#define NN 1000
#define NP 1024
#define TPB 512          // 8 waves; thread tid owns rows 2*tid and 2*tid+1
#define TT 16384         // LDS-staged input length

typedef unsigned int u32;
typedef unsigned long long u64;
typedef _Float16 half2v __attribute__((ext_vector_type(2)));

// S[NN][NN] row-major fp32 -> ST16[j][i] fp16, column j contiguous over padded
// row i (stride 1024 halves = 2KB). ALL NP columns written; cols >= NN are zero
// so they serve as no-op padding targets for the unrolled gather.
__global__ void transpose_S_f16(const float* __restrict__ S, _Float16* __restrict__ ST) {
    int idx = blockIdx.x * blockDim.x + threadIdx.x;   // 0 .. NP*NP-1
    int j = idx >> 10;          // column 0..1023
    int i = idx & (NP - 1);     // row 0..1023
    float val = (i < NN && j < NN) ? S[i * NN + j] : 0.0f;
    ST[(j << 10) + i] = (_Float16)val;   // RTE
}

__device__ __forceinline__ void acc_pair(u32 p, float& A0, float& A1) {
#if __has_builtin(__builtin_amdgcn_fdot2)
    union { u32 u; half2v h; } cv; cv.u = p;
    const half2v E0 = {(_Float16)1.0f, (_Float16)0.0f};
    const half2v E1 = {(_Float16)0.0f, (_Float16)1.0f};
    A0 = __builtin_amdgcn_fdot2(cv.h, E0, A0, false);
    A1 = __builtin_amdgcn_fdot2(cv.h, E1, A1, false);
#else
    union { u32 u; _Float16 h[2]; } cv; cv.u = p;
    A0 += (float)cv.h[0];
    A1 += (float)cv.h[1];
#endif
}

__global__ void __launch_bounds__(TPB) izhikevich_sim(
    const float* __restrict__ data, const float* __restrict__ U,
    const _Float16* __restrict__ ST,
    const float* __restrict__ a, const float* __restrict__ b,
    const float* __restrict__ c, const float* __restrict__ d,
    const float* __restrict__ v0, const float* __restrict__ u0,
    float* __restrict__ out_states, float* __restrict__ out_v,
    float* __restrict__ out_u, float* __restrict__ out_fir, int T)
{
    __shared__ float sdata[TT];        // input currents staged once (64 KB)
    __shared__ u64 wmb[2][16];         // parity-buffered masks: [par][0..7]=even rows, [8..15]=odd
    __shared__ int fidxw[8][1040];     // per-wave private fired list (full K + pad!)

    const int tid  = threadIdx.x;
    const int w    = tid >> 6;
    const int lane = tid & 63;
    const int r0   = tid << 1;
    const bool act = (r0 < NN);

    // stage data[] into LDS (vectorized, one time)
    {
        const int nv = T >> 2;
        const float4* d4 = (const float4*)data;
        float4* s4 = (float4*)sdata;
        for (int n = tid; n < nv && (n << 2) < TT; n += TPB) s4[n] = d4[n];
        for (int n = (nv << 2) + tid; n < T && n < TT; n += TPB) sdata[n] = data[n];
    }

    float v0r = 0.f, v1r = 0.f, u0r = 0.f, u1r = 0.f;
    float a0 = 0.f, a1 = 0.f, b0 = 0.f, b1 = 0.f, c0 = 0.f, c1 = 0.f;
    float d0 = 0.f, d1 = 0.f, U0 = 0.f, U1 = 0.f;
    if (act) {
        float2 t2;
        t2 = *(const float2*)&v0[r0]; v0r = t2.x; v1r = t2.y;
        t2 = *(const float2*)&u0[r0]; u0r = t2.x; u1r = t2.y;
        t2 = *(const float2*)&a[r0];  a0 = t2.x;  a1 = t2.y;
        t2 = *(const float2*)&b[r0];  b0 = t2.x;  b1 = t2.y;
        t2 = *(const float2*)&c[r0];  c0 = t2.x;  c1 = t2.y;
        t2 = *(const float2*)&d[r0];  d0 = t2.x;  d1 = t2.y;
        t2 = *(const float2*)&U[r0];  U0 = t2.x;  U1 = t2.y;
    }
    __syncthreads();   // sdata ready

    const u32* __restrict__ STu = (const u32*)ST;  // u32 [j<<9 + tid] = rows 2tid,2tid+1
    int* __restrict__ fw = fidxw[w];

    for (int t = 0; t < T; ++t) {
        const int par = t & 1;
        // --- fired masks at start of step t ---
        const bool f0 = act && (v0r >= 30.0f);
        const bool f1 = act && (v1r >= 30.0f);
        const u64 bal0 = __ballot(f0);
        const u64 bal1 = __ballot(f1);
        if (lane == 0) { wmb[par][w] = bal0; wmb[par][w + 8] = bal1; }
        // reference applies reset twice: v=c (idempotent), u += 2*d
        if (f0) { v0r = c0; u0r += 2.0f * d0; }
        if (f1) { v1r = c1; u1r += 2.0f * d1; }
        __syncthreads();                          // ONE barrier per step: masks ready

        // --- wave-private decode: lanes 0..15 expand ALL masks into fw ---
        u64 m = 0; int pc = 0, incl = 0;
        if (lane < 16) {
            m = wmb[par][lane];                   // 0..7 even-row words, 8..15 odd
            pc = __popcll(m);
            incl = pc;
            #pragma unroll
            for (int off = 1; off < 16; off <<= 1) {
                int o = __shfl_up(incl, off);
                if (lane >= off) incl += o;
            }
        }
        const int K  = __shfl(incl, 15);          // broadcast to all 64 lanes
        const int K8 = (K + 7) & ~7;
        if (lane < 16) {
            int base = incl - pc;
            const int rowbase = (lane & 7) << 7;
            const int odd = lane >> 3;
            while (m) {
                int bit = __builtin_ctzll(m); m &= m - 1;
                fw[base++] = rowbase + (bit << 1) + odd;
            }
        }
        if (lane == 0) {
            for (int p = K; p < K8; ++p) fw[p] = NN;   // zero-column pads
        }
        __asm__ volatile("s_waitcnt lgkmcnt(0)" ::: "memory");  // wave-local LDS RAW
        __builtin_amdgcn_sched_barrier(0);

        // --- gather: unroll 8, two accumulator pairs for load parallelism ---
        const float xt = (t < TT) ? sdata[t] : data[t];
        float I0 = xt * U0, I1 = xt * U1;
        float J0 = 0.0f, J1 = 0.0f;
        for (int n = 0; n < K8; n += 8) {
            const int j0 = fw[n + 0] << 9;
            const int j1 = fw[n + 1] << 9;
            const int j2 = fw[n + 2] << 9;
            const int j3 = fw[n + 3] << 9;
            const int j4 = fw[n + 4] << 9;
            const int j5 = fw[n + 5] << 9;
            const int j6 = fw[n + 6] << 9;
            const int j7 = fw[n + 7] << 9;
            const u32 p0 = STu[j0 + tid];
            const u32 p1 = STu[j1 + tid];
            const u32 p2 = STu[j2 + tid];
            const u32 p3 = STu[j3 + tid];
            const u32 p4 = STu[j4 + tid];
            const u32 p5 = STu[j5 + tid];
            const u32 p6 = STu[j6 + tid];
            const u32 p7 = STu[j7 + tid];
            acc_pair(p0, I0, I1); acc_pair(p1, J0, J1);
            acc_pair(p2, I0, I1); acc_pair(p3, J0, J1);
            acc_pair(p4, I0, I1); acc_pair(p5, J0, J1);
            acc_pair(p6, I0, I1); acc_pair(p7, J0, J1);
        }
        I0 += J0; I1 += J1;

        // --- update + outputs ---
        if (act) {
            v0r = v0r + 0.5f * (0.04f * v0r * v0r + 5.0f * v0r + 140.0f - u0r + I0);
            u0r = u0r + a0 * (b0 * v0r - u0r);
            v1r = v1r + 0.5f * (0.04f * v1r * v1r + 5.0f * v1r + 140.0f - u1r + I1);
            u1r = u1r + a1 * (b1 * v1r - u1r);
            union { float2 f; u64 u; } st, fr;
            st.f.x = (v0r >= 30.0f) ? 1.0f : 0.0f;
            st.f.y = (v1r >= 30.0f) ? 1.0f : 0.0f;
            fr.f.x = f0 ? 1.0f : 0.0f;
            fr.f.y = f1 ? 1.0f : 0.0f;
            __builtin_nontemporal_store(st.u, (u64*)&out_states[(size_t)t * NN + r0]);
            __builtin_nontemporal_store(fr.u, (u64*)&out_fir[(size_t)t * NN + r0]);
        }
        // hazard note: wmb[par] for step t is re-written only at step t+2; that
        // writer has passed barrier(t+1), which every reader of step t reached
        // only after finishing decode(t). fidxw is wave-private. -> one
        // __syncthreads per step is sufficient.
    }

    if (act) {
        float2 vv, uu;
        vv.x = v0r; vv.y = v1r;
        uu.x = u0r; uu.y = u1r;
        *(float2*)&out_v[r0] = vv;
        *(float2*)&out_u[r0] = uu;
    }
}

extern "C" void kernel_launch(void* const* d_in, const int* in_sizes, int n_in,
                              void* d_out, int out_size, void* d_ws, size_t ws_size,
                              hipStream_t stream) {
    const float* data = (const float*)d_in[0];
    const float* U    = (const float*)d_in[1];
    const float* S    = (const float*)d_in[2];
    const float* a    = (const float*)d_in[3];
    const float* b    = (const float*)d_in[4];
    const float* c    = (const float*)d_in[5];
    const float* dd   = (const float*)d_in[6];
    const float* v0   = (const float*)d_in[7];
    const float* u0   = (const float*)d_in[8];
    const int T = in_sizes[0];   // 16384

    _Float16* ST = (_Float16*)d_ws;   // NP*NP halves = 2 MB

    float* out        = (float*)d_out;
    float* out_states = out;                          // [T, NN]
    float* out_v      = out + (size_t)T * NN;         // [NN]
    float* out_u      = out_v + NN;                   // [NN]
    float* out_fir    = out_u + NN;                   // [T, NN]

    hipLaunchKernelGGL(transpose_S_f16, dim3((NP * NP) / 256), dim3(256), 0, stream, S, ST);
    hipLaunchKernelGGL(izhikevich_sim, dim3(1), dim3(TPB), 0, stream,
                       data, U, ST, a, b, c, dd, v0, u0,
                       out_states, out_v, out_u, out_fir, T);
}

// Round 9
// 20479.405 us; speedup vs baseline: 1.0950x; 1.0950x over previous
//
#include <hip/hip_runtime.h>
#include <stdint.h>

#define NN 1000
#define NP 1024
#define TPB 512          // 8 waves; thread tid owns rows 2*tid and 2*tid+1
#define TT 16384         // LDS-staged input length
#define ZPAD (1008 << 11)  // byte offset of an all-zero padding column

typedef unsigned int u32;
typedef unsigned long long u64;
typedef _Float16 half2v __attribute__((ext_vector_type(2)));

// S[NN][NN] row-major fp32 -> ST16[j][i] fp16, column j contiguous over padded
// row i (stride 1024 halves = 2KB = j<<11 bytes). ALL NP columns written; cols
// >= NN are zero so they serve as no-op padding targets for the unrolled gather.
__global__ void transpose_S_f16(const float* __restrict__ S, _Float16* __restrict__ ST) {
    int idx = blockIdx.x * blockDim.x + threadIdx.x;   // 0 .. NP*NP-1
    int j = idx >> 10;          // column 0..1023
    int i = idx & (NP - 1);     // row 0..1023
    float val = (i < NN && j < NN) ? S[i * NN + j] : 0.0f;
    ST[(j << 10) + i] = (_Float16)val;   // RTE
}

__device__ __forceinline__ void acc_pair(u32 p, float& A0, float& A1) {
#if __has_builtin(__builtin_amdgcn_fdot2)
    union { u32 u; half2v h; } cv; cv.u = p;
    const half2v E0 = {(_Float16)1.0f, (_Float16)0.0f};
    const half2v E1 = {(_Float16)0.0f, (_Float16)1.0f};
    A0 = __builtin_amdgcn_fdot2(cv.h, E0, A0, false);
    A1 = __builtin_amdgcn_fdot2(cv.h, E1, A1, false);
#else
    union { u32 u; _Float16 h[2]; } cv; cv.u = p;
    A0 += (float)cv.h[0];
    A1 += (float)cv.h[1];
#endif
}

__global__ void __launch_bounds__(TPB) izhikevich_sim(
    const float* __restrict__ data, const float* __restrict__ U,
    const _Float16* __restrict__ ST,
    const float* __restrict__ a, const float* __restrict__ b,
    const float* __restrict__ c, const float* __restrict__ d,
    const float* __restrict__ v0, const float* __restrict__ u0,
    float* __restrict__ out_states, float* __restrict__ out_v,
    float* __restrict__ out_u, float* __restrict__ out_fir, int T)
{
    __shared__ float sdata[TT];        // input currents staged once (64 KB)
    __shared__ u64 wm0[8];             // fired mask, even rows of wave w's span
    __shared__ u64 wm1[8];             // odd rows
    __shared__ int fidx[NP + 32];      // fired-column BYTE offsets + pad room
    __shared__ int sKtot;              // padded (x16) fired count

    const int tid  = threadIdx.x;
    const int w    = tid >> 6;
    const int lane = tid & 63;
    const int r0   = tid << 1;
    const bool act = (r0 < NN);
    const int tid4 = tid << 2;         // byte offset of this thread's u32 in a column

    // stage data[] into LDS (vectorized, one time)
    {
        const int nv = T >> 2;
        const float4* d4 = (const float4*)data;
        float4* s4 = (float4*)sdata;
        for (int n = tid; n < nv && (n << 2) < TT; n += TPB) s4[n] = d4[n];
        for (int n = (nv << 2) + tid; n < T && n < TT; n += TPB) sdata[n] = data[n];
    }

    float v0r = 0.f, v1r = 0.f, u0r = 0.f, u1r = 0.f;
    float a0 = 0.f, a1 = 0.f, b0 = 0.f, b1 = 0.f, c0 = 0.f, c1 = 0.f;
    float d0 = 0.f, d1 = 0.f, U0 = 0.f, U1 = 0.f;
    if (act) {
        float2 t2;
        t2 = *(const float2*)&v0[r0]; v0r = t2.x; v1r = t2.y;
        t2 = *(const float2*)&u0[r0]; u0r = t2.x; u1r = t2.y;
        t2 = *(const float2*)&a[r0];  a0 = t2.x;  a1 = t2.y;
        t2 = *(const float2*)&b[r0];  b0 = t2.x;  b1 = t2.y;
        t2 = *(const float2*)&c[r0];  c0 = t2.x;  c1 = t2.y;
        t2 = *(const float2*)&d[r0];  d0 = t2.x;  d1 = t2.y;
        t2 = *(const float2*)&U[r0];  U0 = t2.x;  U1 = t2.y;
    }
    __syncthreads();   // sdata ready

    const char* __restrict__ STb = (const char*)ST;

    for (int t = 0; t < T; ++t) {
        // --- fired masks at start of step t ---
        const bool f0 = act && (v0r >= 30.0f);
        const bool f1 = act && (v1r >= 30.0f);
        const u64 bal0 = __ballot(f0);
        const u64 bal1 = __ballot(f1);
        if (lane == 0) { wm0[w] = bal0; wm1[w] = bal1; }
        // reference applies reset twice: v=c (idempotent), u += 2*d
        if (f0) { v0r = c0; u0r += 2.0f * d0; }
        if (f1) { v1r = c1; u1r += 2.0f * d1; }
        __syncthreads();                          // barrier 1: masks ready

        // --- decode on wave 0: lanes 0..15 expand masks, flat compaction ---
        if (w == 0) {
            u64 m = 0; int pc = 0, incl = 0;
            if (lane < 16) {
                m = (lane < 8) ? wm0[lane] : wm1[lane - 8];
                pc = __popcll(m);
                incl = pc;
                #pragma unroll
                for (int off = 1; off < 16; off <<= 1) {
                    int o = __shfl_up(incl, off);
                    if (lane >= off) incl += o;
                }
            }
            const int K = __shfl(incl, 15);       // total fired, broadcast
            if (lane < 16) {
                int base = incl - pc;
                const int rowbase = (lane & 7) << 7;
                const int odd = lane >> 3;
                while (m) {
                    int bit = __builtin_ctzll(m); m &= m - 1;
                    fidx[base++] = (rowbase + (bit << 1) + odd) << 11;  // byte offset
                }
            } else if (lane < 31) {
                fidx[K + (lane - 16)] = ZPAD;     // 15 pads cover any x16 round-up
            } else if (lane == 31) {
                sKtot = (K + 15) & ~15;
            }
        }
        __syncthreads();                          // barrier 2: fidx/sKtot ready

        // --- gather: unroll 16, four accumulator pairs for load parallelism ---
        const float xt = (t < TT) ? sdata[t] : data[t];
        float I0 = xt * U0, I1 = xt * U1;
        float J0 = 0.0f, J1 = 0.0f;
        float P0 = 0.0f, P1 = 0.0f;
        float Q0 = 0.0f, Q1 = 0.0f;
        const int ktot = sKtot;
        for (int n = 0; n < ktot; n += 16) {
            const int o0  = fidx[n + 0];
            const int o1  = fidx[n + 1];
            const int o2  = fidx[n + 2];
            const int o3  = fidx[n + 3];
            const int o4  = fidx[n + 4];
            const int o5  = fidx[n + 5];
            const int o6  = fidx[n + 6];
            const int o7  = fidx[n + 7];
            const int o8  = fidx[n + 8];
            const int o9  = fidx[n + 9];
            const int o10 = fidx[n + 10];
            const int o11 = fidx[n + 11];
            const int o12 = fidx[n + 12];
            const int o13 = fidx[n + 13];
            const int o14 = fidx[n + 14];
            const int o15 = fidx[n + 15];
            const u32 p0  = *(const u32*)(STb + o0  + tid4);
            const u32 p1  = *(const u32*)(STb + o1  + tid4);
            const u32 p2  = *(const u32*)(STb + o2  + tid4);
            const u32 p3  = *(const u32*)(STb + o3  + tid4);
            const u32 p4  = *(const u32*)(STb + o4  + tid4);
            const u32 p5  = *(const u32*)(STb + o5  + tid4);
            const u32 p6  = *(const u32*)(STb + o6  + tid4);
            const u32 p7  = *(const u32*)(STb + o7  + tid4);
            const u32 p8  = *(const u32*)(STb + o8  + tid4);
            const u32 p9  = *(const u32*)(STb + o9  + tid4);
            const u32 p10 = *(const u32*)(STb + o10 + tid4);
            const u32 p11 = *(const u32*)(STb + o11 + tid4);
            const u32 p12 = *(const u32*)(STb + o12 + tid4);
            const u32 p13 = *(const u32*)(STb + o13 + tid4);
            const u32 p14 = *(const u32*)(STb + o14 + tid4);
            const u32 p15 = *(const u32*)(STb + o15 + tid4);
            acc_pair(p0,  I0, I1); acc_pair(p1,  J0, J1);
            acc_pair(p2,  P0, P1); acc_pair(p3,  Q0, Q1);
            acc_pair(p4,  I0, I1); acc_pair(p5,  J0, J1);
            acc_pair(p6,  P0, P1); acc_pair(p7,  Q0, Q1);
            acc_pair(p8,  I0, I1); acc_pair(p9,  J0, J1);
            acc_pair(p10, P0, P1); acc_pair(p11, Q0, Q1);
            acc_pair(p12, I0, I1); acc_pair(p13, J0, J1);
            acc_pair(p14, P0, P1); acc_pair(p15, Q0, Q1);
        }
        I0 += J0; I1 += J1;
        P0 += Q0; P1 += Q1;
        I0 += P0; I1 += P1;

        // --- update + outputs ---
        if (act) {
            v0r = v0r + 0.5f * (0.04f * v0r * v0r + 5.0f * v0r + 140.0f - u0r + I0);
            u0r = u0r + a0 * (b0 * v0r - u0r);
            v1r = v1r + 0.5f * (0.04f * v1r * v1r + 5.0f * v1r + 140.0f - u1r + I1);
            u1r = u1r + a1 * (b1 * v1r - u1r);
            union { float2 f; u64 u; } st, fr;
            st.f.x = (v0r >= 30.0f) ? 1.0f : 0.0f;
            st.f.y = (v1r >= 30.0f) ? 1.0f : 0.0f;
            fr.f.x = f0 ? 1.0f : 0.0f;
            fr.f.y = f1 ? 1.0f : 0.0f;
            __builtin_nontemporal_store(st.u, (u64*)&out_states[(size_t)t * NN + r0]);
            __builtin_nontemporal_store(fr.u, (u64*)&out_fir[(size_t)t * NN + r0]);
        }
        // no third barrier: a wave reaching step t+1's mask-write has passed
        // barrier 2 of step t (decode(t) complete); decode(t+1) happens after
        // barrier 1 of step t+1, by which point all gathers of step t are done.
    }

    if (act) {
        float2 vv, uu;
        vv.x = v0r; vv.y = v1r;
        uu.x = u0r; uu.y = u1r;
        *(float2*)&out_v[r0] = vv;
        *(float2*)&out_u[r0] = uu;
    }
}

extern "C" void kernel_launch(void* const* d_in, const int* in_sizes, int n_in,
                              void* d_out, int out_size, void* d_ws, size_t ws_size,
                              hipStream_t stream) {
    const float* data = (const float*)d_in[0];
    const float* U    = (const float*)d_in[1];
    const float* S    = (const float*)d_in[2];
    const float* a    = (const float*)d_in[3];
    const float* b    = (const float*)d_in[4];
    const float* c    = (const float*)d_in[5];
    const float* dd   = (const float*)d_in[6];
    const float* v0   = (const float*)d_in[7];
    const float* u0   = (const float*)d_in[8];
    const int T = in_sizes[0];   // 16384

    _Float16* ST = (_Float16*)d_ws;   // NP*NP halves = 2 MB

    float* out        = (float*)d_out;
    float* out_states = out;                          // [T, NN]
    float* out_v      = out + (size_t)T * NN;         // [NN]
    float* out_u      = out_v + NN;                   // [NN]
    float* out_fir    = out_u + NN;                   // [T, NN]

    hipLaunchKernelGGL(transpose_S_f16, dim3((NP * NP) / 256), dim3(256), 0, stream, S, ST);
    hipLaunchKernelGGL(izhikevich_sim, dim3(1), dim3(TPB), 0, stream,
                       data, U, ST, a, b, c, dd, v0, u0,
                       out_states, out_v, out_u, out_fir, T);
}